// Round 1
// baseline (329.761 us; speedup 1.0000x reference)
//
#include <hip/hip_runtime.h>

#define N_SAMP 48

// One thread per ray. Ray data is contiguous: rgb 36 float4, sigma 12 float4,
// z 12 float4. Fully unrolled over 12 groups of 4 samples so the z register
// array is indexed with compile-time constants only (no scratch spill).
__global__ __launch_bounds__(256) void volrender_kernel(
    const float4* __restrict__ rgb4,    // n_rays * 36 float4
    const float4* __restrict__ sigma4,  // n_rays * 12 float4
    const float4* __restrict__ z4,      // n_rays * 12 float4
    float* __restrict__ out_rgb,        // n_rays * 3 floats
    float* __restrict__ out_depth,      // n_rays floats
    int n_rays)
{
    int ray = blockIdx.x * blockDim.x + threadIdx.x;
    if (ray >= n_rays) return;

    // Preload all 48 z values (each used twice: dist and depth accumulation).
    float zv[N_SAMP];
    float4* zvv = reinterpret_cast<float4*>(zv);
#pragma unroll
    for (int k = 0; k < N_SAMP / 4; ++k)
        zvv[k] = z4[(size_t)ray * (N_SAMP / 4) + k];

    float T = 1.0f;
    float ar = 0.0f, ag = 0.0f, ab = 0.0f, ad = 0.0f;

#pragma unroll
    for (int g = 0; g < N_SAMP / 4; ++g) {
        float4 sg = sigma4[(size_t)ray * (N_SAMP / 4) + g];
        float4 r0 = rgb4[(size_t)ray * 36 + g * 3 + 0];
        float4 r1 = rgb4[(size_t)ray * 36 + g * 3 + 1];
        float4 r2 = rgb4[(size_t)ray * 36 + g * 3 + 2];
        float sig[4] = {sg.x, sg.y, sg.z, sg.w};
        float rr[12] = {r0.x, r0.y, r0.z, r0.w,
                        r1.x, r1.y, r1.z, r1.w,
                        r2.x, r2.y, r2.z, r2.w};
#pragma unroll
        for (int j = 0; j < 4; ++j) {
            const int i = g * 4 + j;
            float dist  = (i == N_SAMP - 1) ? 1e10f : (zv[i + 1] - zv[i]);
            float alpha = 1.0f - __expf(-sig[j] * dist);
            float w     = alpha * T;                 // exclusive-T weight
            T *= (1.0f - alpha + 1e-10f);            // update AFTER using T
            ar = fmaf(w, rr[j * 3 + 0], ar);
            ag = fmaf(w, rr[j * 3 + 1], ag);
            ab = fmaf(w, rr[j * 3 + 2], ab);
            ad = fmaf(w, zv[i], ad);
        }
    }

    out_rgb[(size_t)ray * 3 + 0] = ar;
    out_rgb[(size_t)ray * 3 + 1] = ag;
    out_rgb[(size_t)ray * 3 + 2] = ab;
    out_depth[ray] = ad;
}

extern "C" void kernel_launch(void* const* d_in, const int* in_sizes, int n_in,
                              void* d_out, int out_size, void* d_ws, size_t ws_size,
                              hipStream_t stream) {
    const float4* rgb4   = (const float4*)d_in[0];  // (B,HW,48,3) f32
    const float4* sigma4 = (const float4*)d_in[1];  // (B,HW,48,1) f32
    const float4* z4     = (const float4*)d_in[2];  // (B,HW,48)   f32

    const int n_rays = in_sizes[2] / N_SAMP;        // z_vals flat count / 48

    float* out_rgb   = (float*)d_out;               // first (B,HW,3) flat
    float* out_depth = out_rgb + (size_t)n_rays * 3;// then (B,HW) flat

    const int block = 256;
    const int grid  = (n_rays + block - 1) / block;
    hipLaunchKernelGGL(volrender_kernel, dim3(grid), dim3(block), 0, stream,
                       rgb4, sigma4, z4, out_rgb, out_depth, n_rays);
}

// Round 2
// 282.149 us; speedup vs baseline: 1.1687x; 1.1687x over previous
//
#include <hip/hip_runtime.h>

#define N_SAMP 48
#define TPR 4               // threads per ray
#define SPT (N_SAMP / TPR)  // samples per thread = 12

// 4 threads per ray, 12 consecutive samples each. Wave footprint per load
// instruction is a contiguous 3-9 KB window (16 rays), fully consumed by
// adjacent instructions -> L1-clean coalescing. Sequential transmittance
// cumprod becomes a 4-lane segmented scan via shuffles.
__global__ __launch_bounds__(256) void volrender_kernel(
    const float4* __restrict__ rgb4,    // n_rays * 36 float4
    const float4* __restrict__ sigma4,  // n_rays * 12 float4
    const float4* __restrict__ z4,      // n_rays * 12 float4
    const float*  __restrict__ zf,      // scalar view of z
    float* __restrict__ out_rgb,        // n_rays * 3 floats
    float* __restrict__ out_depth,      // n_rays floats
    int n_rays)
{
    const int tid = blockIdx.x * blockDim.x + threadIdx.x;
    const int ray = tid >> 2;
    const int q   = tid & 3;
    if (ray >= n_rays) return;

    // ---- load this thread's 12 z samples (3 float4) + boundary z ----
    float zloc[SPT];
    float4* zv = reinterpret_cast<float4*>(zloc);
    const size_t zbase = (size_t)ray * 12 + q * 3;
#pragma unroll
    for (int k = 0; k < 3; ++k) zv[k] = z4[zbase + k];

    // first z of the NEXT quarter (needed for the last dist of this quarter)
    float znext = 0.0f;
    if (q < 3) znext = zf[(size_t)ray * N_SAMP + q * SPT + SPT];

    // ---- 12 sigma samples (3 float4) ----
    float sloc[SPT];
    float4* sv = reinterpret_cast<float4*>(sloc);
#pragma unroll
    for (int k = 0; k < 3; ++k) sv[k] = sigma4[zbase + k];

    // ---- 36 rgb values (9 float4) ----
    float rloc[SPT * 3];
    float4* rv = reinterpret_cast<float4*>(rloc);
    const size_t rbase = (size_t)ray * 36 + q * 9;
#pragma unroll
    for (int k = 0; k < 9; ++k) rv[k] = rgb4[rbase + k];

    // ---- local pass: exclusive-T weights within this 12-sample segment ----
    float T = 1.0f;
    float ar = 0.0f, ag = 0.0f, ab = 0.0f, ad = 0.0f;
#pragma unroll
    for (int j = 0; j < SPT; ++j) {
        const float zn   = (j < SPT - 1) ? zloc[j + 1] : znext;
        const bool  last = (j == SPT - 1);
        float dist  = (last && q == TPR - 1) ? 1e10f : (zn - zloc[j]);
        float alpha = 1.0f - __expf(-sloc[j] * dist);
        float w     = alpha * T;
        T *= (1.0f - alpha + 1e-10f);
        ar = fmaf(w, rloc[3 * j + 0], ar);
        ag = fmaf(w, rloc[3 * j + 1], ag);
        ab = fmaf(w, rloc[3 * j + 2], ab);
        ad = fmaf(w, zloc[j], ad);
    }

    // ---- prefix product of segment transmittance across the 4 lanes ----
    const int lane = threadIdx.x & 63;
    const int base = lane & ~3;
    const float P  = T;
    const float P0 = __shfl(P, base + 0);
    const float P1 = __shfl(P, base + 1);
    const float P2 = __shfl(P, base + 2);
    float Tpre = 1.0f;
    if (q > 0) Tpre *= P0;
    if (q > 1) Tpre *= P1;
    if (q > 2) Tpre *= P2;

    ar *= Tpre; ag *= Tpre; ab *= Tpre; ad *= Tpre;

    // ---- reduce the 4 lanes of each ray (xor 1, xor 2 stay in-group) ----
    ar += __shfl_xor(ar, 1); ag += __shfl_xor(ag, 1);
    ab += __shfl_xor(ab, 1); ad += __shfl_xor(ad, 1);
    ar += __shfl_xor(ar, 2); ag += __shfl_xor(ag, 2);
    ab += __shfl_xor(ab, 2); ad += __shfl_xor(ad, 2);

    if (q == 0) {
        out_rgb[(size_t)ray * 3 + 0] = ar;
        out_rgb[(size_t)ray * 3 + 1] = ag;
        out_rgb[(size_t)ray * 3 + 2] = ab;
        out_depth[ray] = ad;
    }
}

extern "C" void kernel_launch(void* const* d_in, const int* in_sizes, int n_in,
                              void* d_out, int out_size, void* d_ws, size_t ws_size,
                              hipStream_t stream) {
    const float4* rgb4   = (const float4*)d_in[0];  // (B,HW,48,3) f32
    const float4* sigma4 = (const float4*)d_in[1];  // (B,HW,48,1) f32
    const float4* z4     = (const float4*)d_in[2];  // (B,HW,48)   f32
    const float*  zf     = (const float*)d_in[2];

    const int n_rays = in_sizes[2] / N_SAMP;

    float* out_rgb   = (float*)d_out;
    float* out_depth = out_rgb + (size_t)n_rays * 3;

    const int block     = 256;
    const int n_threads = n_rays * TPR;
    const int grid      = (n_threads + block - 1) / block;
    hipLaunchKernelGGL(volrender_kernel, dim3(grid), dim3(block), 0, stream,
                       rgb4, sigma4, z4, zf, out_rgb, out_depth, n_rays);
}

// Round 3
// 273.067 us; speedup vs baseline: 1.2076x; 1.0333x over previous
//
#include <hip/hip_runtime.h>

#define N_SAMP 48
#define TPR 4               // threads per ray
#define SPT (N_SAMP / TPR)  // samples per thread = 12
#define RPB 64              // rays per block
#define BLOCK (RPB * TPR)   // 256 threads

// Stage the block's 64 rays (60 KB) into LDS with perfectly coalesced
// block-linear float4 loads (16 cache lines per wave instruction), then
// compute with 4 threads/ray reading fragments from LDS.
// LDS read strides (dwords): z/sigma = 12, rgb = 36 -> both tile all 32
// banks across 8 lanes for ds_read_b128 -> conflict-free.
__global__ __launch_bounds__(BLOCK) void volrender_kernel(
    const float4* __restrict__ rgb4,    // n_rays * 36 float4
    const float4* __restrict__ sigma4,  // n_rays * 12 float4
    const float4* __restrict__ z4,      // n_rays * 12 float4
    float* __restrict__ out_rgb,        // n_rays * 3 floats
    float* __restrict__ out_depth,      // n_rays floats
    int n_rays)
{
    __shared__ float4 z_s[RPB * 12];    //  12 KB
    __shared__ float4 s_s[RPB * 12];    //  12 KB
    __shared__ float4 r_s[RPB * 36];    //  36 KB

    const int t         = threadIdx.x;
    const int block_ray = blockIdx.x * RPB;

    // ---- staging: block-linear, fully coalesced global -> LDS ----
    {
        const size_t zb = (size_t)block_ray * 12;   // float4 units
#pragma unroll
        for (int k = 0; k < 3; ++k)
            z_s[k * BLOCK + t] = z4[zb + (size_t)k * BLOCK + t];
#pragma unroll
        for (int k = 0; k < 3; ++k)
            s_s[k * BLOCK + t] = sigma4[zb + (size_t)k * BLOCK + t];
        const size_t rb = (size_t)block_ray * 36;
#pragma unroll
        for (int k = 0; k < 9; ++k)
            r_s[k * BLOCK + t] = rgb4[rb + (size_t)k * BLOCK + t];
    }
    __syncthreads();

    const int rl  = t >> 2;      // ray within block
    const int q   = t & 3;       // quarter of the ray
    const int ray = block_ray + rl;

    // ---- LDS -> registers: this thread's 12-sample fragment ----
    float zloc[SPT];
    float4* zv = reinterpret_cast<float4*>(zloc);
#pragma unroll
    for (int k = 0; k < 3; ++k) zv[k] = z_s[rl * 12 + q * 3 + k];

    float sloc[SPT];
    float4* sv = reinterpret_cast<float4*>(sloc);
#pragma unroll
    for (int k = 0; k < 3; ++k) sv[k] = s_s[rl * 12 + q * 3 + k];

    float rloc[SPT * 3];
    float4* rv = reinterpret_cast<float4*>(rloc);
#pragma unroll
    for (int k = 0; k < 9; ++k) rv[k] = r_s[rl * 36 + q * 9 + k];

    // first z of the NEXT quarter: neighbor lane's zloc[0]
    const int lane  = threadIdx.x & 63;
    const float znext = __shfl(zloc[0], (lane + 1) & 63);  // unused for q==3

    // ---- local pass: exclusive-T weights within the 12-sample segment ----
    float T = 1.0f;
    float ar = 0.0f, ag = 0.0f, ab = 0.0f, ad = 0.0f;
#pragma unroll
    for (int j = 0; j < SPT; ++j) {
        const float zn   = (j < SPT - 1) ? zloc[j + 1] : znext;
        const bool  last = (j == SPT - 1);
        float dist  = (last && q == TPR - 1) ? 1e10f : (zn - zloc[j]);
        float alpha = 1.0f - __expf(-sloc[j] * dist);
        float w     = alpha * T;
        T *= (1.0f - alpha + 1e-10f);
        ar = fmaf(w, rloc[3 * j + 0], ar);
        ag = fmaf(w, rloc[3 * j + 1], ag);
        ab = fmaf(w, rloc[3 * j + 2], ab);
        ad = fmaf(w, zloc[j], ad);
    }

    // ---- prefix product of segment transmittance across the 4 lanes ----
    const int  base = lane & ~3;
    const float P   = T;
    const float P0  = __shfl(P, base + 0);
    const float P1  = __shfl(P, base + 1);
    const float P2  = __shfl(P, base + 2);
    float Tpre = 1.0f;
    if (q > 0) Tpre *= P0;
    if (q > 1) Tpre *= P1;
    if (q > 2) Tpre *= P2;

    ar *= Tpre; ag *= Tpre; ab *= Tpre; ad *= Tpre;

    // ---- reduce the 4 lanes of each ray ----
    ar += __shfl_xor(ar, 1); ag += __shfl_xor(ag, 1);
    ab += __shfl_xor(ab, 1); ad += __shfl_xor(ad, 1);
    ar += __shfl_xor(ar, 2); ag += __shfl_xor(ag, 2);
    ab += __shfl_xor(ab, 2); ad += __shfl_xor(ad, 2);

    if (q == 0 && ray < n_rays) {
        out_rgb[(size_t)ray * 3 + 0] = ar;
        out_rgb[(size_t)ray * 3 + 1] = ag;
        out_rgb[(size_t)ray * 3 + 2] = ab;
        out_depth[ray] = ad;
    }
}

extern "C" void kernel_launch(void* const* d_in, const int* in_sizes, int n_in,
                              void* d_out, int out_size, void* d_ws, size_t ws_size,
                              hipStream_t stream) {
    const float4* rgb4   = (const float4*)d_in[0];  // (B,HW,48,3) f32
    const float4* sigma4 = (const float4*)d_in[1];  // (B,HW,48,1) f32
    const float4* z4     = (const float4*)d_in[2];  // (B,HW,48)   f32

    const int n_rays = in_sizes[2] / N_SAMP;

    float* out_rgb   = (float*)d_out;
    float* out_depth = out_rgb + (size_t)n_rays * 3;

    const int grid = (n_rays + RPB - 1) / RPB;   // 4096 blocks for 262144 rays
    hipLaunchKernelGGL(volrender_kernel, dim3(grid), dim3(BLOCK), 0, stream,
                       rgb4, sigma4, z4, out_rgb, out_depth, n_rays);
}